// Round 1
// baseline (108.029 us; speedup 1.0000x reference)
//
#include <hip/hip_runtime.h>
#include <math.h>

// Problem constants
#define NTOK   16384   // B*N = 16*1024
#define CIN_   66      // HID + IN_DIM
#define HID_   64
#define NCH    192     // folded columns: [z(64) | r(64) | c(64)]
#define TPB    64      // tokens per block

// ---------------------------------------------------------------------------
// Kernel 1: fold rnn_W[6][198][64] + rnn_b[6][64] into Wf[66][192], bf[192].
// gconv_rnn bug => effective weight = W[:66] + 0.05*(W[66:132]+W[132:198]);
// z uses pair (0,1), r uses (2,3), hc uses (4,5) -> pre-sum the pairs.
// ---------------------------------------------------------------------------
__global__ void fold_weights(const float* __restrict__ rnn_W,
                             const float* __restrict__ rnn_b,
                             float* __restrict__ Wf,
                             float* __restrict__ bf)
{
    int idx = blockIdx.x * blockDim.x + threadIdx.x;
    if (idx >= CIN_ * NCH) return;
    int k = idx / NCH;
    int c = idx - k * NCH;
    int g = c >> 6;          // 0:z 1:r 2:c
    int j = c & 63;
    int i0 = 2 * g, i1 = 2 * g + 1;
    const float s = 0.05f;
    float v = 0.0f;
    v += rnn_W[(i0 * 198 + k) * 64 + j]
       + s * (rnn_W[(i0 * 198 + 66 + k) * 64 + j] + rnn_W[(i0 * 198 + 132 + k) * 64 + j]);
    v += rnn_W[(i1 * 198 + k) * 64 + j]
       + s * (rnn_W[(i1 * 198 + 66 + k) * 64 + j] + rnn_W[(i1 * 198 + 132 + k) * 64 + j]);
    Wf[k * NCH + c] = v;
    if (k == 0) bf[c] = rnn_b[i0 * 64 + j] + rnn_b[i1 * 64 + j];
}

// ---------------------------------------------------------------------------
// Kernel 2: fused GRU cell. 256 blocks x 256 threads; block owns 64 tokens.
// lane (0..63) = token within block; wave (0..3) = wave-uniform channel slice
// so Wf row accesses are uniform -> scalar/s_load path, inner loop is
// v_fmac(acc, s_w, v_c). LDS [k][tok] with stride 65 -> conflict-free.
// ---------------------------------------------------------------------------
__global__ __launch_bounds__(256, 1)
void dgcrm_gru(const float* __restrict__ x,    // [NTOK][2]
               const float* __restrict__ h,    // [NTOK][64]
               const float* __restrict__ Wf,   // [66][192]
               const float* __restrict__ bf,   // [192]
               float* __restrict__ out)        // [NTOK][64]
{
    __shared__ float C[CIN_][TPB + 1];  // combined = [x; h], [k][tok]
    __shared__ float D[CIN_][TPB + 1];  // candidate = [x; r*h]
    __shared__ float Z[HID_][TPB + 1];  // z, then reused as output buffer

    const int tid = threadIdx.x;
    const int t0  = blockIdx.x * TPB;     // first global token of this block

    // ---- stage h (transposed) into C rows 2..65 : coalesced float4 reads ----
    {
        const float4* h4 = (const float4*)(h + (size_t)t0 * HID_);
        for (int i = tid; i < TPB * HID_ / 4; i += 256) {
            float4 v = h4[i];
            int f = i * 4;
            int t = f >> 6;
            int c = f & 63;
            C[2 + c + 0][t] = v.x;
            C[2 + c + 1][t] = v.y;
            C[2 + c + 2][t] = v.z;
            C[2 + c + 3][t] = v.w;
        }
    }
    // ---- stage x into rows 0,1 of both C and D ----
    if (tid < 2 * TPB) {
        int t = tid >> 1, k = tid & 1;
        float v = x[(size_t)(t0 + t) * 2 + k];
        C[k][t] = v;
        D[k][t] = v;
    }
    __syncthreads();

    const int wave = __builtin_amdgcn_readfirstlane(tid >> 6); // 0..3, SGPR
    const int lane = tid & 63;                                 // token

    // =================== phase 1: z (ch 0..63) and r (ch 64..127) ==========
    {
        const int ch0 = wave * 32;           // uniform
        float acc[32];
        #pragma unroll
        for (int j = 0; j < 32; ++j) acc[j] = bf[ch0 + j];

        for (int k = 0; k < CIN_; ++k) {
            float ck = C[k][lane];
            const float* wrow = Wf + k * NCH + ch0;  // uniform address
            #pragma unroll
            for (int j = 0; j < 32; ++j) acc[j] = fmaf(ck, wrow[j], acc[j]);
        }

        if (wave < 2) {
            // z channels ch0..ch0+31
            #pragma unroll
            for (int j = 0; j < 32; ++j) {
                float zv = 1.0f / (1.0f + __expf(-acc[j]));
                Z[ch0 + j][lane] = zv;
            }
        } else {
            // r channels (ch0-64)..(ch0-64)+31 ; write cand = r*h into D
            const int rb = ch0 - 64;
            #pragma unroll
            for (int j = 0; j < 32; ++j) {
                float rv = 1.0f / (1.0f + __expf(-acc[j]));
                D[2 + rb + j][lane] = rv * C[2 + rb + j][lane];
            }
        }
    }
    __syncthreads();

    // =================== phase 2: hc (ch 128..191), combine ================
    {
        const int ch0 = 128 + wave * 16;     // uniform
        float acc[16];
        #pragma unroll
        for (int j = 0; j < 16; ++j) acc[j] = bf[ch0 + j];

        for (int k = 0; k < CIN_; ++k) {
            float ck = D[k][lane];
            const float* wrow = Wf + k * NCH + ch0;  // uniform address
            #pragma unroll
            for (int j = 0; j < 16; ++j) acc[j] = fmaf(ck, wrow[j], acc[j]);
        }

        const int hb = wave * 16;            // hc channel base
        #pragma unroll
        for (int j = 0; j < 16; ++j) {
            float hc = tanhf(acc[j]);
            float zv = Z[hb + j][lane];
            float hv = C[2 + hb + j][lane];
            Z[hb + j][lane] = zv * hv + (1.0f - zv) * hc;  // in-place: out
        }
    }
    __syncthreads();

    // ---- coalesced write-back: out[t0+t][c] = Z[c][t] ----
    for (int i = tid; i < TPB * HID_; i += 256) {
        int t = i >> 6, c = i & 63;
        out[(size_t)(t0 + t) * HID_ + c] = Z[c][t];
    }
}

// ---------------------------------------------------------------------------
extern "C" void kernel_launch(void* const* d_in, const int* in_sizes, int n_in,
                              void* d_out, int out_size, void* d_ws, size_t ws_size,
                              hipStream_t stream)
{
    const float* x     = (const float*)d_in[0];   // [16,1024,2]
    const float* hprev = (const float*)d_in[1];   // [16,1024,64]
    const float* rnn_W = (const float*)d_in[12];  // [6,198,64]
    const float* rnn_b = (const float*)d_in[13];  // [6,64]

    float* Wf = (float*)d_ws;                 // 66*192 floats
    float* bf = Wf + CIN_ * NCH;              // 192 floats

    fold_weights<<<(CIN_ * NCH + 255) / 256, 256, 0, stream>>>(rnn_W, rnn_b, Wf, bf);
    dgcrm_gru<<<NTOK / TPB, 256, 0, stream>>>(x, hprev, Wf, bf, (float*)d_out);
}